// Round 8
// baseline (418.381 us; speedup 1.0000x reference)
//
#include <hip/hip_runtime.h>
#include <math.h>

#define N 512
#define CS 384
#define CZ 128
#define NH 16
#define DH 24
#define HD 384
#define NN (N*N)
#define EPS 1e-5f

// ws layout (float offsets)
#define OFF_AN   0          // a_n [N][CS]
#define OFF_QT   196608     // qT [H][N][D] (pre-scaled by 1/sqrt(24))
#define OFF_KT   393216     // kT [H][N][D]
#define OFF_VT   589824     // vT [H][N][D]
#define OFF_GT   786432     // gT [H][N][D] (sigmoid applied)
#define OFF_OG   983040     // o*g [N][HD]
#define OFF_WZ2  1179648    // g_z*Wz transposed [H][CZ]
#define OFF_SH   1181696    // [H]
#define OFF_BH   1181712    // [H]
#define OFF_BIAS 1181728    // pair bias [H][N][N]

// ---------------- fused: prep (block 256) + LayerNorm of a (blocks 0..255, 2 rows each) ----------------
__global__ void __launch_bounds__(256) ln_prep_kernel(const float* __restrict__ a, const float* __restrict__ g_a,
                                                      const float* __restrict__ b_a, float* __restrict__ an_out,
                                                      const float* __restrict__ g_z, const float* __restrict__ lnb_z,
                                                      const float* __restrict__ Wz, const float* __restrict__ bz,
                                                      float* __restrict__ wz2, float* __restrict__ sh,
                                                      float* __restrict__ bh) {
    __shared__ float ls[NH][17], lb[NH][17];   // prep block
    __shared__ float l1[4], l2[4];             // ln blocks
    const int t = threadIdx.x;
    if (blockIdx.x == 256) {
        for (int i = t; i < NH * CZ; i += 256) {
            int h = i >> 7, c = i & (CZ - 1);
            wz2[h * CZ + c] = g_z[c] * Wz[c * NH + h];
        }
        int h = t >> 4, seg = t & 15;
        float s = 0.f, b = 0.f;
        #pragma unroll
        for (int i = 0; i < 8; ++i) {
            int c = seg * 8 + i;
            float w = Wz[c * NH + h];
            s += g_z[c] * w;
            b += lnb_z[c] * w;
        }
        ls[h][seg] = s; lb[h][seg] = b;
        __syncthreads();
        if (t < NH) {
            float ss = 0.f, bb = 0.f;
            #pragma unroll
            for (int i = 0; i < 16; ++i) { ss += ls[t][i]; bb += lb[t][i]; }
            sh[t] = ss;
            bh[t] = bb + bz[t];
        }
        return;
    }
    const int half = t >> 7;
    const int tr = t & 127;
    const int r = blockIdx.x * 2 + half;
    const float* row = a + r * CS;
    float x0 = row[tr], x1 = row[tr + 128], x2 = row[tr + 256];
    float s1 = x0 + x1 + x2;
    float s2 = x0 * x0 + x1 * x1 + x2 * x2;
    #pragma unroll
    for (int m = 1; m < 64; m <<= 1) {
        s1 += __shfl_xor(s1, m, 64);
        s2 += __shfl_xor(s2, m, 64);
    }
    if ((t & 63) == 0) { l1[t >> 6] = s1; l2[t >> 6] = s2; }
    __syncthreads();
    s1 = l1[half * 2] + l1[half * 2 + 1];
    s2 = l2[half * 2] + l2[half * 2 + 1];
    float mu = s1 * (1.f / CS);
    float var = s2 * (1.f / CS) - mu * mu;
    float rs = rsqrtf(var + EPS);
    float* an = an_out + r * CS;
    an[tr]       = (x0 - mu) * rs * g_a[tr]       + b_a[tr];
    an[tr + 128] = (x1 - mu) * rs * g_a[tr + 128] + b_a[tr + 128];
    an[tr + 256] = (x2 - mu) * rs * g_a[tr + 256] + b_a[tr + 256];
}

// ---------------- qkvg v3: LDS-staged an-tile, 4 cols/thread, 3072 waves (R6, kept) ----------------
__global__ void __launch_bounds__(256) qkvg_kernel(const float* __restrict__ Wq, const float* __restrict__ Wk,
                                                   const float* __restrict__ Wv, const float* __restrict__ Wg,
                                                   const float* __restrict__ bg, const float* __restrict__ an,
                                                   float* __restrict__ qt, float* __restrict__ kt,
                                                   float* __restrict__ vt, float* __restrict__ gt) {
    __shared__ float4 lan[64 * 8];   // 8 KB
    const int t = threadIdx.x;
    const int lane = t & 63;
    const int w = __builtin_amdgcn_readfirstlane(t >> 6);
    const int s = blockIdx.x * 4 + w;     // 0..383 strips
    const int n0 = s * 4;
    const int sel = n0 / HD;              // 0:q 1:k 2:v 3:g
    const int col = n0 - sel * HD;
    const float* Wm = (sel == 0) ? Wq : (sel == 1) ? Wk : (sel == 2) ? Wv : Wg;
    const int m0 = blockIdx.y * 64;
    const int m = m0 + lane;
    const float4* an4 = (const float4*)an;
    float acc[4];
    #pragma unroll
    for (int j = 0; j < 4; ++j) acc[j] = 0.f;
    for (int kb = 0; kb < CS; kb += 32) {
        __syncthreads();
        #pragma unroll
        for (int i = 0; i < 2; ++i) {
            const int idx = i * 256 + t;          // 0..511
            const int r = idx >> 3, c = idx & 7;
            lan[(r << 3) + (c ^ (r & 7))] = an4[(size_t)(m0 + r) * 96 + (kb >> 2) + c];
        }
        __syncthreads();
        float4 av[8];
        #pragma unroll
        for (int i = 0; i < 8; ++i) av[i] = lan[(lane << 3) + (i ^ (lane & 7))];
        #pragma unroll
        for (int i = 0; i < 8; ++i) {
            const float* wr = Wm + (kb + i * 4) * HD + col; // wave-uniform -> s_load
            #pragma unroll
            for (int j = 0; j < 4; ++j) {
                acc[j] += av[i].x * wr[j];
                acc[j] += av[i].y * wr[HD + j];
                acc[j] += av[i].z * wr[2 * HD + j];
                acc[j] += av[i].w * wr[3 * HD + j];
            }
        }
    }
    float* dst = (sel == 0) ? qt : (sel == 1) ? kt : (sel == 2) ? vt : gt;
    if (sel == 3) {
        #pragma unroll
        for (int j = 0; j < 4; ++j) acc[j] = 1.f / (1.f + __expf(-(acc[j] + bg[col + j])));
    } else if (sel == 0) {
        #pragma unroll
        for (int j = 0; j < 4; ++j) acc[j] *= 0.20412414523193153f; // 1/sqrt(24)
    }
    const int h = col / DH, d0 = col - h * DH;
    float* dp = dst + (h * N + m) * DH + d0;
    #pragma unroll
    for (int j = 0; j < 4; ++j) dp[j] = acc[j];
}

// ---------------- pair bias v6: 256-row slab, ZERO-redundancy (1 thread = 1 row, all 16 heads) ----------------
// Stage full 128KB z-slab to LDS coalesced (32 float4/thread, reg-double-buffered 4x8 batches,
// 64KB in flight/CU -> HBM saturates). One sync. Thread t owns row t: 64 lanes read 64 distinct
// rows at same cc = v4's proven 0-conflict XOR pattern. 18 ops/elem (the minimum) vs v4's 24,
// and NO per-wave redundancy (v4 read z 4x from LDS). Occupancy reads ~12% (4 waves/CU) BY
// DESIGN: in-flight-bytes (32KB >> 8.2KB=BW*latency) is what saturates HBM, not wave count.
__global__ void __launch_bounds__(256, 1) pairbias_kernel(const float* __restrict__ z,
                                                          const float* __restrict__ wz2,
                                                          const float* __restrict__ sh,
                                                          const float* __restrict__ bh,
                                                          float* __restrict__ bias) {
    __shared__ float4 lz[256 * 32];   // 128 KB
    const int t = threadIdx.x;
    const int row0 = blockIdx.x * 256;
    const float4* zsrc = (const float4*)z + (size_t)row0 * 32;

#define PB_WR(rr, b) { _Pragma("unroll") for (int i = 0; i < 8; ++i) { \
    const int g4_ = ((b) * 8 + i) * 256 + t; \
    const int r_ = g4_ >> 5, cc_ = g4_ & 31; \
    lz[r_ * 32 + (cc_ ^ (r_ & 31))] = rr[i]; } }

    float4 ra[8], rb[8];
    #pragma unroll
    for (int i = 0; i < 8; ++i) ra[i] = zsrc[(0 * 8 + i) * 256 + t];
    #pragma unroll
    for (int i = 0; i < 8; ++i) rb[i] = zsrc[(1 * 8 + i) * 256 + t];
    PB_WR(ra, 0);
    #pragma unroll
    for (int i = 0; i < 8; ++i) ra[i] = zsrc[(2 * 8 + i) * 256 + t];
    PB_WR(rb, 1);
    #pragma unroll
    for (int i = 0; i < 8; ++i) rb[i] = zsrc[(3 * 8 + i) * 256 + t];
    PB_WR(ra, 2);
    PB_WR(rb, 3);
#undef PB_WR
    __syncthreads();

    const char* lzb = (const char*)lz;
    const unsigned base = (unsigned)(t * 512 + ((t & 31) << 4));  // byte addr of (row t, slot t&31)
    float s1 = 0.f, s2 = 0.f;
    float d[16];
    #pragma unroll
    for (int j = 0; j < 16; ++j) d[j] = 0.f;
    #pragma unroll 4
    for (int cc = 0; cc < 32; ++cc) {
        float4 v = *(const float4*)(lzb + (base ^ (unsigned)(cc << 4)));
        s1 += v.x + v.y + v.z + v.w;
        s2 += v.x * v.x + v.y * v.y + v.z * v.z + v.w * v.w;
        #pragma unroll
        for (int j = 0; j < 16; ++j) {
            const float4 wv = ((const float4*)(wz2 + j * CZ))[cc];  // uniform -> s_load
            d[j] += v.x * wv.x + v.y * wv.y + v.z * wv.z + v.w * wv.w;
        }
    }
    const float mu = s1 * (1.f / CZ);
    const float var = s2 * (1.f / CZ) - mu * mu;
    const float rs = rsqrtf(var + EPS);
    const int row = row0 + t;
    #pragma unroll
    for (int j = 0; j < 16; ++j)
        bias[j * NN + row] = rs * (d[j] - mu * sh[j]) + bh[j];   // wave: 256B contiguous per head
}

// ---------------- attn v2: flash-style with LDS-staged K/V tiles (R6, kept) ----------------
__global__ void __launch_bounds__(256, 4) attn_kernel(const float* __restrict__ qt, const float* __restrict__ kt,
                                                      const float* __restrict__ vt, const float* __restrict__ gt,
                                                      const float* __restrict__ bias, float* __restrict__ og) {
    __shared__ float4 lzK[128 * 8];   // 16 KB
    __shared__ float4 lzV[128 * 8];   // 16 KB
    const int t = threadIdx.x;
    const int lane = t & 63;
    const int w = __builtin_amdgcn_readfirstlane(t >> 6);
    const int qhalf = lane >> 5;     // 0/1
    const int klane = lane & 31;
    const int h = blockIdx.y;
    const int q = blockIdx.x * 8 + w * 2 + qhalf;
    const float* qT = qt + h * N * DH;
    const float4* kT4 = (const float4*)(kt + h * N * DH);
    const float4* vT4 = (const float4*)(vt + h * N * DH);
    const float* brow = bias + h * NN + q * N;

    float qv[DH];
    #pragma unroll
    for (int d6 = 0; d6 < 6; ++d6) {
        float4 t4 = ((const float4*)(qT + q * DH))[d6];
        qv[d6 * 4 + 0] = t4.x; qv[d6 * 4 + 1] = t4.y; qv[d6 * 4 + 2] = t4.z; qv[d6 * 4 + 3] = t4.w;
    }
    float m_run = -1e30f, l_run = 0.f;
    float acc[DH];
    #pragma unroll
    for (int d = 0; d < DH; ++d) acc[d] = 0.f;

    for (int tile = 0; tile < 4; ++tile) {
        __syncthreads();
        const int kt0 = tile * 128;
        #pragma unroll
        for (int i = 0; i < 3; ++i) {
            const int idx = i * 256 + t;       // 0..767 (= r*6+c, rows contiguous)
            const int r = idx / 6, c = idx - r * 6;
            const int slot = (r << 3) + (c ^ (r & 7));
            lzK[slot] = kT4[kt0 * 6 + idx];
            lzV[slot] = vT4[kt0 * 6 + idx];
        }
        __syncthreads();
        float sc[4];
        #pragma unroll
        for (int j = 0; j < 4; ++j) {
            const int kk = j * 32 + klane;
            const float4* kr = lzK + (kk << 3);
            const int x = kk & 7;
            float4 k0 = kr[0 ^ x], k1 = kr[1 ^ x], k2 = kr[2 ^ x],
                   k3 = kr[3 ^ x], k4 = kr[4 ^ x], k5 = kr[5 ^ x];
            float s = qv[0]*k0.x + qv[1]*k0.y + qv[2]*k0.z + qv[3]*k0.w
                    + qv[4]*k1.x + qv[5]*k1.y + qv[6]*k1.z + qv[7]*k1.w
                    + qv[8]*k2.x + qv[9]*k2.y + qv[10]*k2.z + qv[11]*k2.w
                    + qv[12]*k3.x + qv[13]*k3.y + qv[14]*k3.z + qv[15]*k3.w
                    + qv[16]*k4.x + qv[17]*k4.y + qv[18]*k4.z + qv[19]*k4.w
                    + qv[20]*k5.x + qv[21]*k5.y + qv[22]*k5.z + qv[23]*k5.w;
            sc[j] = s + brow[kt0 + kk];
        }
        float tm = fmaxf(fmaxf(sc[0], sc[1]), fmaxf(sc[2], sc[3]));
        #pragma unroll
        for (int m = 1; m < 32; m <<= 1) tm = fmaxf(tm, __shfl_xor(tm, m, 64));
        const float m_new = fmaxf(m_run, tm);
        const float scale = __expf(m_run - m_new);
        l_run *= scale;
        #pragma unroll
        for (int d = 0; d < DH; ++d) acc[d] *= scale;
        float p[4], ps = 0.f;
        #pragma unroll
        for (int j = 0; j < 4; ++j) { p[j] = __expf(sc[j] - m_new); ps += p[j]; }
        #pragma unroll
        for (int m = 1; m < 32; m <<= 1) ps += __shfl_xor(ps, m, 64);
        l_run += ps;
        m_run = m_new;
        #pragma unroll
        for (int j = 0; j < 4; ++j) {
            const int kk = j * 32 + klane;
            const float4* vr = lzV + (kk << 3);
            const int x = kk & 7;
            float4 v0 = vr[0 ^ x], v1 = vr[1 ^ x], v2 = vr[2 ^ x],
                   v3 = vr[3 ^ x], v4 = vr[4 ^ x], v5 = vr[5 ^ x];
            const float pj = p[j];
            acc[0] += pj*v0.x;  acc[1] += pj*v0.y;  acc[2] += pj*v0.z;  acc[3] += pj*v0.w;
            acc[4] += pj*v1.x;  acc[5] += pj*v1.y;  acc[6] += pj*v1.z;  acc[7] += pj*v1.w;
            acc[8] += pj*v2.x;  acc[9] += pj*v2.y;  acc[10] += pj*v2.z; acc[11] += pj*v2.w;
            acc[12] += pj*v3.x; acc[13] += pj*v3.y; acc[14] += pj*v3.z; acc[15] += pj*v3.w;
            acc[16] += pj*v4.x; acc[17] += pj*v4.y; acc[18] += pj*v4.z; acc[19] += pj*v4.w;
            acc[20] += pj*v5.x; acc[21] += pj*v5.y; acc[22] += pj*v5.z; acc[23] += pj*v5.w;
        }
    }
    #pragma unroll
    for (int m = 1; m < 32; m <<= 1) {
        #pragma unroll
        for (int d = 0; d < DH; ++d) acc[d] += __shfl_xor(acc[d], m, 64);
    }
    const float inv = 1.f / l_run;
    float o = 0.f;
    #pragma unroll
    for (int d = 0; d < DH; ++d) o = (klane == d) ? acc[d] : o;
    if (klane < DH) {
        float g = gt[h * N * DH + q * DH + klane];
        og[q * HD + h * DH + klane] = o * inv * g;
    }
}

// ---------------- out_gemm v3: LDS-staged og-tile, 2 cols/thread, 1536 waves (R6, kept) ----------------
__global__ void __launch_bounds__(256) out_gemm_kernel(const float* __restrict__ Wo, const float* __restrict__ bo,
                                                       const float* __restrict__ og, float* __restrict__ out) {
    __shared__ float4 lo[64 * 8];    // 8 KB
    const int t = threadIdx.x;
    const int lane = t & 63;
    const int w = __builtin_amdgcn_readfirstlane(t >> 6);
    const int s = blockIdx.x * 4 + w;     // 0..191 strips of 2 cols
    const int c0 = s * 2;
    const int m0 = blockIdx.y * 64;
    const int m = m0 + lane;
    const float4* og4 = (const float4*)og;
    float acc[2];
    acc[0] = 0.f; acc[1] = 0.f;
    for (int kb = 0; kb < HD; kb += 32) {
        __syncthreads();
        #pragma unroll
        for (int i = 0; i < 2; ++i) {
            const int idx = i * 256 + t;          // 0..511
            const int r = idx >> 3, c = idx & 7;
            lo[(r << 3) + (c ^ (r & 7))] = og4[(size_t)(m0 + r) * 96 + (kb >> 2) + c];
        }
        __syncthreads();
        float4 av[8];
        #pragma unroll
        for (int i = 0; i < 8; ++i) av[i] = lo[(lane << 3) + (i ^ (lane & 7))];
        #pragma unroll
        for (int i = 0; i < 8; ++i) {
            const float* wr = Wo + (kb + i * 4) * CS + c0; // uniform -> s_load
            #pragma unroll
            for (int j = 0; j < 2; ++j) {
                acc[j] += av[i].x * wr[j];
                acc[j] += av[i].y * wr[CS + j];
                acc[j] += av[i].z * wr[2 * CS + j];
                acc[j] += av[i].w * wr[3 * CS + j];
            }
        }
    }
    #pragma unroll
    for (int j = 0; j < 2; ++j) out[m * CS + c0 + j] = acc[j] + bo[c0 + j];
}

extern "C" void kernel_launch(void* const* d_in, const int* in_sizes, int n_in,
                              void* d_out, int out_size, void* d_ws, size_t ws_size,
                              hipStream_t stream) {
    const float* a    = (const float*)d_in[0];
    const float* z    = (const float*)d_in[1];
    const float* g_a  = (const float*)d_in[2];
    const float* b_a  = (const float*)d_in[3];
    const float* g_z  = (const float*)d_in[4];
    const float* b_z  = (const float*)d_in[5];
    const float* Wz   = (const float*)d_in[6];
    const float* bz   = (const float*)d_in[7];
    const float* Wq   = (const float*)d_in[8];
    const float* Wk   = (const float*)d_in[9];
    const float* Wv   = (const float*)d_in[10];
    const float* Wg   = (const float*)d_in[11];
    const float* bg   = (const float*)d_in[12];
    const float* Wo   = (const float*)d_in[13];
    const float* bo   = (const float*)d_in[14];
    float* ws  = (float*)d_ws;
    float* out = (float*)d_out;

    float* an   = ws + OFF_AN;
    float* qt   = ws + OFF_QT;
    float* kt   = ws + OFF_KT;
    float* vt   = ws + OFF_VT;
    float* gt   = ws + OFF_GT;
    float* ogp  = ws + OFF_OG;
    float* wz2  = ws + OFF_WZ2;
    float* shp  = ws + OFF_SH;
    float* bhp  = ws + OFF_BH;
    float* bias = ws + OFF_BIAS;

    hipLaunchKernelGGL(ln_prep_kernel, dim3(257),    dim3(256), 0, stream,
                       a, g_a, b_a, an, g_z, b_z, Wz, bz, wz2, shp, bhp);
    hipLaunchKernelGGL(qkvg_kernel,    dim3(96, 8),  dim3(256), 0, stream,
                       Wq, Wk, Wv, Wg, bg, an, qt, kt, vt, gt);
    hipLaunchKernelGGL(pairbias_kernel, dim3(1024),  dim3(256), 0, stream,
                       z, wz2, shp, bhp, bias);
    hipLaunchKernelGGL(attn_kernel,    dim3(64, 16), dim3(256), 0, stream,
                       qt, kt, vt, gt, bias, ogp);
    hipLaunchKernelGGL(out_gemm_kernel, dim3(48, 8), dim3(256), 0, stream,
                       Wo, bo, ogp, out);
}

// Round 9
// 329.798 us; speedup vs baseline: 1.2686x; 1.2686x over previous
//
#include <hip/hip_runtime.h>
#include <math.h>

#define N 512
#define CS 384
#define CZ 128
#define NH 16
#define DH 24
#define HD 384
#define NN (N*N)
#define EPS 1e-5f

// ws layout (float offsets)
#define OFF_AN   0          // a_n [N][CS]
#define OFF_QT   196608     // qT [H][N][D] (pre-scaled by 1/sqrt(24))
#define OFF_KT   393216     // kT [H][N][D]
#define OFF_VT   589824     // vT [H][N][D]
#define OFF_GT   786432     // gT [H][N][D] (sigmoid applied)
#define OFF_OG   983040     // o*g [N][HD]
#define OFF_WZ2  1179648    // g_z*Wz transposed [H][CZ]
#define OFF_SH   1181696    // [H]
#define OFF_BH   1181712    // [H]
#define OFF_BIAS 1181728    // pair bias [H][N][N]

// ---------------- fused: prep (block 256) + LayerNorm of a (blocks 0..255, 2 rows each) ----------------
__global__ void __launch_bounds__(256) ln_prep_kernel(const float* __restrict__ a, const float* __restrict__ g_a,
                                                      const float* __restrict__ b_a, float* __restrict__ an_out,
                                                      const float* __restrict__ g_z, const float* __restrict__ lnb_z,
                                                      const float* __restrict__ Wz, const float* __restrict__ bz,
                                                      float* __restrict__ wz2, float* __restrict__ sh,
                                                      float* __restrict__ bh) {
    __shared__ float ls[NH][17], lb[NH][17];   // prep block
    __shared__ float l1[4], l2[4];             // ln blocks
    const int t = threadIdx.x;
    if (blockIdx.x == 256) {
        for (int i = t; i < NH * CZ; i += 256) {
            int h = i >> 7, c = i & (CZ - 1);
            wz2[h * CZ + c] = g_z[c] * Wz[c * NH + h];
        }
        int h = t >> 4, seg = t & 15;
        float s = 0.f, b = 0.f;
        #pragma unroll
        for (int i = 0; i < 8; ++i) {
            int c = seg * 8 + i;
            float w = Wz[c * NH + h];
            s += g_z[c] * w;
            b += lnb_z[c] * w;
        }
        ls[h][seg] = s; lb[h][seg] = b;
        __syncthreads();
        if (t < NH) {
            float ss = 0.f, bb = 0.f;
            #pragma unroll
            for (int i = 0; i < 16; ++i) { ss += ls[t][i]; bb += lb[t][i]; }
            sh[t] = ss;
            bh[t] = bb + bz[t];
        }
        return;
    }
    const int half = t >> 7;
    const int tr = t & 127;
    const int r = blockIdx.x * 2 + half;
    const float* row = a + r * CS;
    float x0 = row[tr], x1 = row[tr + 128], x2 = row[tr + 256];
    float s1 = x0 + x1 + x2;
    float s2 = x0 * x0 + x1 * x1 + x2 * x2;
    #pragma unroll
    for (int m = 1; m < 64; m <<= 1) {
        s1 += __shfl_xor(s1, m, 64);
        s2 += __shfl_xor(s2, m, 64);
    }
    if ((t & 63) == 0) { l1[t >> 6] = s1; l2[t >> 6] = s2; }
    __syncthreads();
    s1 = l1[half * 2] + l1[half * 2 + 1];
    s2 = l2[half * 2] + l2[half * 2 + 1];
    float mu = s1 * (1.f / CS);
    float var = s2 * (1.f / CS) - mu * mu;
    float rs = rsqrtf(var + EPS);
    float* an = an_out + r * CS;
    an[tr]       = (x0 - mu) * rs * g_a[tr]       + b_a[tr];
    an[tr + 128] = (x1 - mu) * rs * g_a[tr + 128] + b_a[tr + 128];
    an[tr + 256] = (x2 - mu) * rs * g_a[tr + 256] + b_a[tr + 256];
}

// ---------------- qkvg v3: LDS-staged an-tile, 4 cols/thread, 3072 waves (R6, kept) ----------------
__global__ void __launch_bounds__(256) qkvg_kernel(const float* __restrict__ Wq, const float* __restrict__ Wk,
                                                   const float* __restrict__ Wv, const float* __restrict__ Wg,
                                                   const float* __restrict__ bg, const float* __restrict__ an,
                                                   float* __restrict__ qt, float* __restrict__ kt,
                                                   float* __restrict__ vt, float* __restrict__ gt) {
    __shared__ float4 lan[64 * 8];   // 8 KB
    const int t = threadIdx.x;
    const int lane = t & 63;
    const int w = __builtin_amdgcn_readfirstlane(t >> 6);
    const int s = blockIdx.x * 4 + w;     // 0..383 strips
    const int n0 = s * 4;
    const int sel = n0 / HD;              // 0:q 1:k 2:v 3:g
    const int col = n0 - sel * HD;
    const float* Wm = (sel == 0) ? Wq : (sel == 1) ? Wk : (sel == 2) ? Wv : Wg;
    const int m0 = blockIdx.y * 64;
    const int m = m0 + lane;
    const float4* an4 = (const float4*)an;
    float acc[4];
    #pragma unroll
    for (int j = 0; j < 4; ++j) acc[j] = 0.f;
    for (int kb = 0; kb < CS; kb += 32) {
        __syncthreads();
        #pragma unroll
        for (int i = 0; i < 2; ++i) {
            const int idx = i * 256 + t;          // 0..511
            const int r = idx >> 3, c = idx & 7;
            lan[(r << 3) + (c ^ (r & 7))] = an4[(size_t)(m0 + r) * 96 + (kb >> 2) + c];
        }
        __syncthreads();
        float4 av[8];
        #pragma unroll
        for (int i = 0; i < 8; ++i) av[i] = lan[(lane << 3) + (i ^ (lane & 7))];
        #pragma unroll
        for (int i = 0; i < 8; ++i) {
            const float* wr = Wm + (kb + i * 4) * HD + col; // wave-uniform -> s_load
            #pragma unroll
            for (int j = 0; j < 4; ++j) {
                acc[j] += av[i].x * wr[j];
                acc[j] += av[i].y * wr[HD + j];
                acc[j] += av[i].z * wr[2 * HD + j];
                acc[j] += av[i].w * wr[3 * HD + j];
            }
        }
    }
    float* dst = (sel == 0) ? qt : (sel == 1) ? kt : (sel == 2) ? vt : gt;
    if (sel == 3) {
        #pragma unroll
        for (int j = 0; j < 4; ++j) acc[j] = 1.f / (1.f + __expf(-(acc[j] + bg[col + j])));
    } else if (sel == 0) {
        #pragma unroll
        for (int j = 0; j < 4; ++j) acc[j] *= 0.20412414523193153f; // 1/sqrt(24)
    }
    const int h = col / DH, d0 = col - h * DH;
    float* dp = dst + (h * N + m) * DH + d0;
    #pragma unroll
    for (int j = 0; j < 4; ++j) dp[j] = acc[j];
}

// ---------------- pair bias v7: v4 structure + weights in LDS (kills in-loop s_load serialization) ----------------
// v4 proven geometry: 64-row tile, 4 thr/row (wave w -> heads 4w..4w+3), cheap-XOR z reads
// (0-conflict: 256 dwords/32 banks = 8/bank = minimum), coalesced staging, contiguous writes,
// 4 blocks/CU. NEW: wz2 (8 KB) staged once into LDS; hot loop reads weights via uniform-address
// ds_read_b128 (broadcast, conflict-free, deep lgkm pipelining) instead of 128 s_load_dwordx4
// per pass that serialized on SMEM latency (~512 SGPRs needed to preload vs ~102 budget).
__global__ void __launch_bounds__(256, 4) pairbias_kernel(const float* __restrict__ z,
                                                          const float* __restrict__ wz2,
                                                          const float* __restrict__ sh,
                                                          const float* __restrict__ bh,
                                                          float* __restrict__ bias) {
    __shared__ float4 lz[64 * 32];   // 32 KB z tile
    __shared__ float4 lw[NH * 32];   // 8 KB weights: lw[h*32+cc]
    const int t = threadIdx.x;
    const int l = t & 63;                                      // row within tile
    const int w = __builtin_amdgcn_readfirstlane(t >> 6);      // head group (wave-uniform)
    const int h0 = w * 4;
    const int row0 = blockIdx.x * 64;

    // stage weights (512 float4, 2/thread) — one-time, L2-hit after first blocks
    const float4* w4 = (const float4*)wz2;
    lw[t] = w4[t];
    lw[t + 256] = w4[t + 256];

    // stage z: 2048 float4, 8/thread, 4KB contiguous per wave-instr (v4 verbatim)
    const float4* zsrc = (const float4*)(z + (size_t)row0 * CZ);
    #pragma unroll
    for (int i = 0; i < 8; ++i) {
        const int g4 = i * 256 + t;            // 0..2047
        float4 v = zsrc[g4];
        const int r = g4 >> 5, cc = g4 & 31;
        lz[r * 32 + (cc ^ (r & 31))] = v;
    }
    __syncthreads();

    const unsigned base = (unsigned)(l * 512 + ((l & 31) << 4));  // byte addr of (row l, slot l&31)
    const char* lzb = (const char*)lz;
    const float4* lwh = lw + h0 * 32;   // wave-uniform base
    float s1 = 0.f, s2 = 0.f;
    float d0 = 0.f, d1 = 0.f, d2 = 0.f, d3 = 0.f;
    #pragma unroll
    for (int cc = 0; cc < 32; ++cc) {
        float4 v = *(const float4*)(lzb + (base ^ (unsigned)(cc << 4)));
        s1 += v.x + v.y + v.z + v.w;
        s2 += v.x * v.x + v.y * v.y + v.z * v.z + v.w * v.w;
        const float4 w0 = lwh[cc];          // uniform addr -> broadcast ds_read_b128
        const float4 w1 = lwh[32 + cc];
        const float4 w2 = lwh[64 + cc];
        const float4 w3 = lwh[96 + cc];
        d0 += v.x * w0.x + v.y * w0.y + v.z * w0.z + v.w * w0.w;
        d1 += v.x * w1.x + v.y * w1.y + v.z * w1.z + v.w * w1.w;
        d2 += v.x * w2.x + v.y * w2.y + v.z * w2.z + v.w * w2.w;
        d3 += v.x * w3.x + v.y * w3.y + v.z * w3.z + v.w * w3.w;
    }
    const float mu = s1 * (1.f / CZ);
    const float var = s2 * (1.f / CZ) - mu * mu;
    const float rs = rsqrtf(var + EPS);
    const int row = row0 + l;
    bias[(h0 + 0) * NN + row] = rs * (d0 - mu * sh[h0 + 0]) + bh[h0 + 0];
    bias[(h0 + 1) * NN + row] = rs * (d1 - mu * sh[h0 + 1]) + bh[h0 + 1];
    bias[(h0 + 2) * NN + row] = rs * (d2 - mu * sh[h0 + 2]) + bh[h0 + 2];
    bias[(h0 + 3) * NN + row] = rs * (d3 - mu * sh[h0 + 3]) + bh[h0 + 3];
}

// ---------------- attn v2: flash-style with LDS-staged K/V tiles (R6, kept) ----------------
__global__ void __launch_bounds__(256, 4) attn_kernel(const float* __restrict__ qt, const float* __restrict__ kt,
                                                      const float* __restrict__ vt, const float* __restrict__ gt,
                                                      const float* __restrict__ bias, float* __restrict__ og) {
    __shared__ float4 lzK[128 * 8];   // 16 KB
    __shared__ float4 lzV[128 * 8];   // 16 KB
    const int t = threadIdx.x;
    const int lane = t & 63;
    const int w = __builtin_amdgcn_readfirstlane(t >> 6);
    const int qhalf = lane >> 5;     // 0/1
    const int klane = lane & 31;
    const int h = blockIdx.y;
    const int q = blockIdx.x * 8 + w * 2 + qhalf;
    const float* qT = qt + h * N * DH;
    const float4* kT4 = (const float4*)(kt + h * N * DH);
    const float4* vT4 = (const float4*)(vt + h * N * DH);
    const float* brow = bias + h * NN + q * N;

    float qv[DH];
    #pragma unroll
    for (int d6 = 0; d6 < 6; ++d6) {
        float4 t4 = ((const float4*)(qT + q * DH))[d6];
        qv[d6 * 4 + 0] = t4.x; qv[d6 * 4 + 1] = t4.y; qv[d6 * 4 + 2] = t4.z; qv[d6 * 4 + 3] = t4.w;
    }
    float m_run = -1e30f, l_run = 0.f;
    float acc[DH];
    #pragma unroll
    for (int d = 0; d < DH; ++d) acc[d] = 0.f;

    for (int tile = 0; tile < 4; ++tile) {
        __syncthreads();
        const int kt0 = tile * 128;
        #pragma unroll
        for (int i = 0; i < 3; ++i) {
            const int idx = i * 256 + t;       // 0..767 (= r*6+c, rows contiguous)
            const int r = idx / 6, c = idx - r * 6;
            const int slot = (r << 3) + (c ^ (r & 7));
            lzK[slot] = kT4[kt0 * 6 + idx];
            lzV[slot] = vT4[kt0 * 6 + idx];
        }
        __syncthreads();
        float sc[4];
        #pragma unroll
        for (int j = 0; j < 4; ++j) {
            const int kk = j * 32 + klane;
            const float4* kr = lzK + (kk << 3);
            const int x = kk & 7;
            float4 k0 = kr[0 ^ x], k1 = kr[1 ^ x], k2 = kr[2 ^ x],
                   k3 = kr[3 ^ x], k4 = kr[4 ^ x], k5 = kr[5 ^ x];
            float s = qv[0]*k0.x + qv[1]*k0.y + qv[2]*k0.z + qv[3]*k0.w
                    + qv[4]*k1.x + qv[5]*k1.y + qv[6]*k1.z + qv[7]*k1.w
                    + qv[8]*k2.x + qv[9]*k2.y + qv[10]*k2.z + qv[11]*k2.w
                    + qv[12]*k3.x + qv[13]*k3.y + qv[14]*k3.z + qv[15]*k3.w
                    + qv[16]*k4.x + qv[17]*k4.y + qv[18]*k4.z + qv[19]*k4.w
                    + qv[20]*k5.x + qv[21]*k5.y + qv[22]*k5.z + qv[23]*k5.w;
            sc[j] = s + brow[kt0 + kk];
        }
        float tm = fmaxf(fmaxf(sc[0], sc[1]), fmaxf(sc[2], sc[3]));
        #pragma unroll
        for (int m = 1; m < 32; m <<= 1) tm = fmaxf(tm, __shfl_xor(tm, m, 64));
        const float m_new = fmaxf(m_run, tm);
        const float scale = __expf(m_run - m_new);
        l_run *= scale;
        #pragma unroll
        for (int d = 0; d < DH; ++d) acc[d] *= scale;
        float p[4], ps = 0.f;
        #pragma unroll
        for (int j = 0; j < 4; ++j) { p[j] = __expf(sc[j] - m_new); ps += p[j]; }
        #pragma unroll
        for (int m = 1; m < 32; m <<= 1) ps += __shfl_xor(ps, m, 64);
        l_run += ps;
        m_run = m_new;
        #pragma unroll
        for (int j = 0; j < 4; ++j) {
            const int kk = j * 32 + klane;
            const float4* vr = lzV + (kk << 3);
            const int x = kk & 7;
            float4 v0 = vr[0 ^ x], v1 = vr[1 ^ x], v2 = vr[2 ^ x],
                   v3 = vr[3 ^ x], v4 = vr[4 ^ x], v5 = vr[5 ^ x];
            const float pj = p[j];
            acc[0] += pj*v0.x;  acc[1] += pj*v0.y;  acc[2] += pj*v0.z;  acc[3] += pj*v0.w;
            acc[4] += pj*v1.x;  acc[5] += pj*v1.y;  acc[6] += pj*v1.z;  acc[7] += pj*v1.w;
            acc[8] += pj*v2.x;  acc[9] += pj*v2.y;  acc[10] += pj*v2.z; acc[11] += pj*v2.w;
            acc[12] += pj*v3.x; acc[13] += pj*v3.y; acc[14] += pj*v3.z; acc[15] += pj*v3.w;
            acc[16] += pj*v4.x; acc[17] += pj*v4.y; acc[18] += pj*v4.z; acc[19] += pj*v4.w;
            acc[20] += pj*v5.x; acc[21] += pj*v5.y; acc[22] += pj*v5.z; acc[23] += pj*v5.w;
        }
    }
    #pragma unroll
    for (int m = 1; m < 32; m <<= 1) {
        #pragma unroll
        for (int d = 0; d < DH; ++d) acc[d] += __shfl_xor(acc[d], m, 64);
    }
    const float inv = 1.f / l_run;
    float o = 0.f;
    #pragma unroll
    for (int d = 0; d < DH; ++d) o = (klane == d) ? acc[d] : o;
    if (klane < DH) {
        float g = gt[h * N * DH + q * DH + klane];
        og[q * HD + h * DH + klane] = o * inv * g;
    }
}

// ---------------- out_gemm v3: LDS-staged og-tile, 2 cols/thread, 1536 waves (R6, kept) ----------------
__global__ void __launch_bounds__(256) out_gemm_kernel(const float* __restrict__ Wo, const float* __restrict__ bo,
                                                       const float* __restrict__ og, float* __restrict__ out) {
    __shared__ float4 lo[64 * 8];    // 8 KB
    const int t = threadIdx.x;
    const int lane = t & 63;
    const int w = __builtin_amdgcn_readfirstlane(t >> 6);
    const int s = blockIdx.x * 4 + w;     // 0..191 strips of 2 cols
    const int c0 = s * 2;
    const int m0 = blockIdx.y * 64;
    const int m = m0 + lane;
    const float4* og4 = (const float4*)og;
    float acc[2];
    acc[0] = 0.f; acc[1] = 0.f;
    for (int kb = 0; kb < HD; kb += 32) {
        __syncthreads();
        #pragma unroll
        for (int i = 0; i < 2; ++i) {
            const int idx = i * 256 + t;          // 0..511
            const int r = idx >> 3, c = idx & 7;
            lo[(r << 3) + (c ^ (r & 7))] = og4[(size_t)(m0 + r) * 96 + (kb >> 2) + c];
        }
        __syncthreads();
        float4 av[8];
        #pragma unroll
        for (int i = 0; i < 8; ++i) av[i] = lo[(lane << 3) + (i ^ (lane & 7))];
        #pragma unroll
        for (int i = 0; i < 8; ++i) {
            const float* wr = Wo + (kb + i * 4) * CS + c0; // uniform -> s_load
            #pragma unroll
            for (int j = 0; j < 2; ++j) {
                acc[j] += av[i].x * wr[j];
                acc[j] += av[i].y * wr[CS + j];
                acc[j] += av[i].z * wr[2 * CS + j];
                acc[j] += av[i].w * wr[3 * CS + j];
            }
        }
    }
    #pragma unroll
    for (int j = 0; j < 2; ++j) out[m * CS + c0 + j] = acc[j] + bo[c0 + j];
}

extern "C" void kernel_launch(void* const* d_in, const int* in_sizes, int n_in,
                              void* d_out, int out_size, void* d_ws, size_t ws_size,
                              hipStream_t stream) {
    const float* a    = (const float*)d_in[0];
    const float* z    = (const float*)d_in[1];
    const float* g_a  = (const float*)d_in[2];
    const float* b_a  = (const float*)d_in[3];
    const float* g_z  = (const float*)d_in[4];
    const float* b_z  = (const float*)d_in[5];
    const float* Wz   = (const float*)d_in[6];
    const float* bz   = (const float*)d_in[7];
    const float* Wq   = (const float*)d_in[8];
    const float* Wk   = (const float*)d_in[9];
    const float* Wv   = (const float*)d_in[10];
    const float* Wg   = (const float*)d_in[11];
    const float* bg   = (const float*)d_in[12];
    const float* Wo   = (const float*)d_in[13];
    const float* bo   = (const float*)d_in[14];
    float* ws  = (float*)d_ws;
    float* out = (float*)d_out;

    float* an   = ws + OFF_AN;
    float* qt   = ws + OFF_QT;
    float* kt   = ws + OFF_KT;
    float* vt   = ws + OFF_VT;
    float* gt   = ws + OFF_GT;
    float* ogp  = ws + OFF_OG;
    float* wz2  = ws + OFF_WZ2;
    float* shp  = ws + OFF_SH;
    float* bhp  = ws + OFF_BH;
    float* bias = ws + OFF_BIAS;

    hipLaunchKernelGGL(ln_prep_kernel, dim3(257),    dim3(256), 0, stream,
                       a, g_a, b_a, an, g_z, b_z, Wz, bz, wz2, shp, bhp);
    hipLaunchKernelGGL(qkvg_kernel,    dim3(96, 8),  dim3(256), 0, stream,
                       Wq, Wk, Wv, Wg, bg, an, qt, kt, vt, gt);
    hipLaunchKernelGGL(pairbias_kernel, dim3(4096),  dim3(256), 0, stream,
                       z, wz2, shp, bhp, bias);
    hipLaunchKernelGGL(attn_kernel,    dim3(64, 16), dim3(256), 0, stream,
                       qt, kt, vt, gt, bias, ogp);
    hipLaunchKernelGGL(out_gemm_kernel, dim3(48, 8), dim3(256), 0, stream,
                       Wo, bo, ogp, out);
}

// Round 10
// 325.289 us; speedup vs baseline: 1.2862x; 1.0139x over previous
//
#include <hip/hip_runtime.h>
#include <math.h>

#define N 512
#define CS 384
#define CZ 128
#define NH 16
#define DH 24
#define HD 384
#define NN (N*N)
#define EPS 1e-5f

// ws layout (float offsets)
#define OFF_AN   0          // a_n [N][CS]
#define OFF_QT   196608     // qT [H][N][D] (pre-scaled by 1/sqrt(24))
#define OFF_KT   393216     // kT [H][N][D]
#define OFF_VT   589824     // vT [H][N][D]
#define OFF_GT   786432     // gT [H][N][D] (sigmoid applied)
#define OFF_OG   983040     // o*g [N][HD]
#define OFF_WZ2  1179648    // g_z*Wz transposed [H][CZ]
#define OFF_SH   1181696    // [H]
#define OFF_BH   1181712    // [H]
#define OFF_BIAS 1181728    // pair bias [H][N][N]

// async 16B global->LDS (gfx950): LDS dest is wave-uniform base + lane*16; global addr per-lane.
#define GLOAD_LDS16(gp, lp) \
    __builtin_amdgcn_global_load_lds((const __attribute__((address_space(1))) void*)(gp), \
                                     (__attribute__((address_space(3))) void*)(lp), 16, 0, 0)

// ---------------- fused: prep (block 256) + LayerNorm of a (blocks 0..255, 2 rows each) ----------------
__global__ void __launch_bounds__(256) ln_prep_kernel(const float* __restrict__ a, const float* __restrict__ g_a,
                                                      const float* __restrict__ b_a, float* __restrict__ an_out,
                                                      const float* __restrict__ g_z, const float* __restrict__ lnb_z,
                                                      const float* __restrict__ Wz, const float* __restrict__ bz,
                                                      float* __restrict__ wz2, float* __restrict__ sh,
                                                      float* __restrict__ bh) {
    __shared__ float ls[NH][17], lb[NH][17];   // prep block
    __shared__ float l1[4], l2[4];             // ln blocks
    const int t = threadIdx.x;
    if (blockIdx.x == 256) {
        for (int i = t; i < NH * CZ; i += 256) {
            int h = i >> 7, c = i & (CZ - 1);
            wz2[h * CZ + c] = g_z[c] * Wz[c * NH + h];
        }
        int h = t >> 4, seg = t & 15;
        float s = 0.f, b = 0.f;
        #pragma unroll
        for (int i = 0; i < 8; ++i) {
            int c = seg * 8 + i;
            float w = Wz[c * NH + h];
            s += g_z[c] * w;
            b += lnb_z[c] * w;
        }
        ls[h][seg] = s; lb[h][seg] = b;
        __syncthreads();
        if (t < NH) {
            float ss = 0.f, bb = 0.f;
            #pragma unroll
            for (int i = 0; i < 16; ++i) { ss += ls[t][i]; bb += lb[t][i]; }
            sh[t] = ss;
            bh[t] = bb + bz[t];
        }
        return;
    }
    const int half = t >> 7;
    const int tr = t & 127;
    const int r = blockIdx.x * 2 + half;
    const float* row = a + r * CS;
    float x0 = row[tr], x1 = row[tr + 128], x2 = row[tr + 256];
    float s1 = x0 + x1 + x2;
    float s2 = x0 * x0 + x1 * x1 + x2 * x2;
    #pragma unroll
    for (int m = 1; m < 64; m <<= 1) {
        s1 += __shfl_xor(s1, m, 64);
        s2 += __shfl_xor(s2, m, 64);
    }
    if ((t & 63) == 0) { l1[t >> 6] = s1; l2[t >> 6] = s2; }
    __syncthreads();
    s1 = l1[half * 2] + l1[half * 2 + 1];
    s2 = l2[half * 2] + l2[half * 2 + 1];
    float mu = s1 * (1.f / CS);
    float var = s2 * (1.f / CS) - mu * mu;
    float rs = rsqrtf(var + EPS);
    float* an = an_out + r * CS;
    an[tr]       = (x0 - mu) * rs * g_a[tr]       + b_a[tr];
    an[tr + 128] = (x1 - mu) * rs * g_a[tr + 128] + b_a[tr + 128];
    an[tr + 256] = (x2 - mu) * rs * g_a[tr + 256] + b_a[tr + 256];
}

// ---------------- qkvg v3: LDS-staged an-tile, 4 cols/thread, 3072 waves (R6, kept) ----------------
__global__ void __launch_bounds__(256) qkvg_kernel(const float* __restrict__ Wq, const float* __restrict__ Wk,
                                                   const float* __restrict__ Wv, const float* __restrict__ Wg,
                                                   const float* __restrict__ bg, const float* __restrict__ an,
                                                   float* __restrict__ qt, float* __restrict__ kt,
                                                   float* __restrict__ vt, float* __restrict__ gt) {
    __shared__ float4 lan[64 * 8];   // 8 KB
    const int t = threadIdx.x;
    const int lane = t & 63;
    const int w = __builtin_amdgcn_readfirstlane(t >> 6);
    const int s = blockIdx.x * 4 + w;     // 0..383 strips
    const int n0 = s * 4;
    const int sel = n0 / HD;              // 0:q 1:k 2:v 3:g
    const int col = n0 - sel * HD;
    const float* Wm = (sel == 0) ? Wq : (sel == 1) ? Wk : (sel == 2) ? Wv : Wg;
    const int m0 = blockIdx.y * 64;
    const int m = m0 + lane;
    const float4* an4 = (const float4*)an;
    float acc[4];
    #pragma unroll
    for (int j = 0; j < 4; ++j) acc[j] = 0.f;
    for (int kb = 0; kb < CS; kb += 32) {
        __syncthreads();
        #pragma unroll
        for (int i = 0; i < 2; ++i) {
            const int idx = i * 256 + t;          // 0..511
            const int r = idx >> 3, c = idx & 7;
            lan[(r << 3) + (c ^ (r & 7))] = an4[(size_t)(m0 + r) * 96 + (kb >> 2) + c];
        }
        __syncthreads();
        float4 av[8];
        #pragma unroll
        for (int i = 0; i < 8; ++i) av[i] = lan[(lane << 3) + (i ^ (lane & 7))];
        #pragma unroll
        for (int i = 0; i < 8; ++i) {
            const float* wr = Wm + (kb + i * 4) * HD + col; // wave-uniform -> s_load
            #pragma unroll
            for (int j = 0; j < 4; ++j) {
                acc[j] += av[i].x * wr[j];
                acc[j] += av[i].y * wr[HD + j];
                acc[j] += av[i].z * wr[2 * HD + j];
                acc[j] += av[i].w * wr[3 * HD + j];
            }
        }
    }
    float* dst = (sel == 0) ? qt : (sel == 1) ? kt : (sel == 2) ? vt : gt;
    if (sel == 3) {
        #pragma unroll
        for (int j = 0; j < 4; ++j) acc[j] = 1.f / (1.f + __expf(-(acc[j] + bg[col + j])));
    } else if (sel == 0) {
        #pragma unroll
        for (int j = 0; j < 4; ++j) acc[j] *= 0.20412414523193153f; // 1/sqrt(24)
    }
    const int h = col / DH, d0 = col - h * DH;
    float* dp = dst + (h * N + m) * DH + d0;
    #pragma unroll
    for (int j = 0; j < 4; ++j) dp[j] = acc[j];
}

// ---------------- pair bias v8: v4 structure + global_load_lds async staging ----------------
// v4 proven geometry (71us best): 64-row tile, 4 thr/row (wave w -> heads 4w..4w+3), XOR z reads
// (0-conflict), s_load weights, contiguous writes, 4 blocks/CU. SINGLE CHANGE: staging is now
// async global_load_lds width=16 — no ds_write phase, no VGPR round-trip (Common-mistake #1).
// Rule #21: LDS dest linear (chunk*1024 + lane*16), SOURCE pre-inverse-swizzled, read swizzled —
// same XOR involution. LDS offset X=512r+16s must hold z[row0+r][4*(s^(r&31))..] so compute's
// base^(cc<<4) read (base = l*512+((l&31)<<4)) lands on logical column cc.
__global__ void __launch_bounds__(256, 4) pairbias_kernel(const float* __restrict__ z,
                                                          const float* __restrict__ wz2,
                                                          const float* __restrict__ sh,
                                                          const float* __restrict__ bh,
                                                          float* __restrict__ bias) {
    __shared__ float4 lz[64 * 32];   // 32 KB
    const int t = threadIdx.x;
    const int lane = t & 63;
    const int l = t & 63;                                      // row within tile
    const int w = __builtin_amdgcn_readfirstlane(t >> 6);      // head group (wave-uniform)
    const int h0 = w * 4;
    const int row0 = blockIdx.x * 64;

    const char* zb = (const char*)(z + (size_t)row0 * CZ);
    #pragma unroll
    for (int i = 0; i < 8; ++i) {
        const int chunk = w * 8 + i;               // wave-uniform (0..31)
        const int r = chunk * 2 + (lane >> 5);     // tile row this lane's 16B belongs to
        const int s = lane & 31;                   // physical slot within row
        const char* g = zb + r * 512 + ((s ^ (r & 31)) << 4);   // inverse-swizzled source
        GLOAD_LDS16(g, (char*)lz + chunk * 1024);  // linear dest: base + lane*16
    }
    __syncthreads();   // compiler drains vmcnt before barrier

    const unsigned base = (unsigned)(l * 512 + ((l & 31) << 4));
    const char* lzb = (const char*)lz;
    float s1 = 0.f, s2 = 0.f;
    float d0 = 0.f, d1 = 0.f, d2 = 0.f, d3 = 0.f;
    #pragma unroll
    for (int cc = 0; cc < 32; ++cc) {
        float4 v = *(const float4*)(lzb + (base ^ (unsigned)(cc << 4)));
        s1 += v.x + v.y + v.z + v.w;
        s2 += v.x * v.x + v.y * v.y + v.z * v.z + v.w * v.w;
        const float4 w0 = ((const float4*)(wz2 + (h0 + 0) * CZ))[cc];  // uniform -> s_load
        const float4 w1 = ((const float4*)(wz2 + (h0 + 1) * CZ))[cc];
        const float4 w2 = ((const float4*)(wz2 + (h0 + 2) * CZ))[cc];
        const float4 w3 = ((const float4*)(wz2 + (h0 + 3) * CZ))[cc];
        d0 += v.x * w0.x + v.y * w0.y + v.z * w0.z + v.w * w0.w;
        d1 += v.x * w1.x + v.y * w1.y + v.z * w1.z + v.w * w1.w;
        d2 += v.x * w2.x + v.y * w2.y + v.z * w2.z + v.w * w2.w;
        d3 += v.x * w3.x + v.y * w3.y + v.z * w3.z + v.w * w3.w;
    }
    const float mu = s1 * (1.f / CZ);
    const float var = s2 * (1.f / CZ) - mu * mu;
    const float rs = rsqrtf(var + EPS);
    const int row = row0 + l;
    bias[(h0 + 0) * NN + row] = rs * (d0 - mu * sh[h0 + 0]) + bh[h0 + 0];
    bias[(h0 + 1) * NN + row] = rs * (d1 - mu * sh[h0 + 1]) + bh[h0 + 1];
    bias[(h0 + 2) * NN + row] = rs * (d2 - mu * sh[h0 + 2]) + bh[h0 + 2];
    bias[(h0 + 3) * NN + row] = rs * (d3 - mu * sh[h0 + 3]) + bh[h0 + 3];
}

// ---------------- attn v3: flash-style, PADDED [128][9]-float4 K/V tiles (conflict-free) ----------------
// R9 evidence: 3.93M LDS bank conflicts. Old layout row stride 128B -> 32r vanishes mod 32 banks;
// writes were ~8-way conflicted. Padded stride 144B: start bank = 4(r+c) mod 32 rotates per row ->
// writes uniform; reads (lane kk, elems 0..5 of row kk) cover all 32 banks per 8-lane group.
__global__ void __launch_bounds__(256, 4) attn_kernel(const float* __restrict__ qt, const float* __restrict__ kt,
                                                      const float* __restrict__ vt, const float* __restrict__ gt,
                                                      const float* __restrict__ bias, float* __restrict__ og) {
    __shared__ float4 lzK[128 * 9];   // 18 KB
    __shared__ float4 lzV[128 * 9];   // 18 KB
    const int t = threadIdx.x;
    const int lane = t & 63;
    const int w = __builtin_amdgcn_readfirstlane(t >> 6);
    const int qhalf = lane >> 5;     // 0/1
    const int klane = lane & 31;
    const int h = blockIdx.y;
    const int q = blockIdx.x * 8 + w * 2 + qhalf;
    const float* qT = qt + h * N * DH;
    const float4* kT4 = (const float4*)(kt + h * N * DH);
    const float4* vT4 = (const float4*)(vt + h * N * DH);
    const float* brow = bias + h * NN + q * N;

    float qv[DH];
    #pragma unroll
    for (int d6 = 0; d6 < 6; ++d6) {
        float4 t4 = ((const float4*)(qT + q * DH))[d6];
        qv[d6 * 4 + 0] = t4.x; qv[d6 * 4 + 1] = t4.y; qv[d6 * 4 + 2] = t4.z; qv[d6 * 4 + 3] = t4.w;
    }
    float m_run = -1e30f, l_run = 0.f;
    float acc[DH];
    #pragma unroll
    for (int d = 0; d < DH; ++d) acc[d] = 0.f;

    for (int tile = 0; tile < 4; ++tile) {
        __syncthreads();
        const int kt0 = tile * 128;
        #pragma unroll
        for (int i = 0; i < 3; ++i) {
            const int idx = i * 256 + t;       // 0..767 (= r*6+c, rows contiguous)
            const int r = idx / 6, c = idx - r * 6;
            const int slot = r * 9 + c;        // padded row: bank start rotates with r
            lzK[slot] = kT4[kt0 * 6 + idx];
            lzV[slot] = vT4[kt0 * 6 + idx];
        }
        __syncthreads();
        float sc[4];
        #pragma unroll
        for (int j = 0; j < 4; ++j) {
            const int kk = j * 32 + klane;
            const float4* kr = lzK + kk * 9;
            float4 k0 = kr[0], k1 = kr[1], k2 = kr[2], k3 = kr[3], k4 = kr[4], k5 = kr[5];
            float s = qv[0]*k0.x + qv[1]*k0.y + qv[2]*k0.z + qv[3]*k0.w
                    + qv[4]*k1.x + qv[5]*k1.y + qv[6]*k1.z + qv[7]*k1.w
                    + qv[8]*k2.x + qv[9]*k2.y + qv[10]*k2.z + qv[11]*k2.w
                    + qv[12]*k3.x + qv[13]*k3.y + qv[14]*k3.z + qv[15]*k3.w
                    + qv[16]*k4.x + qv[17]*k4.y + qv[18]*k4.z + qv[19]*k4.w
                    + qv[20]*k5.x + qv[21]*k5.y + qv[22]*k5.z + qv[23]*k5.w;
            sc[j] = s + brow[kt0 + kk];
        }
        float tm = fmaxf(fmaxf(sc[0], sc[1]), fmaxf(sc[2], sc[3]));
        #pragma unroll
        for (int m = 1; m < 32; m <<= 1) tm = fmaxf(tm, __shfl_xor(tm, m, 64));
        const float m_new = fmaxf(m_run, tm);
        const float scale = __expf(m_run - m_new);
        l_run *= scale;
        #pragma unroll
        for (int d = 0; d < DH; ++d) acc[d] *= scale;
        float p[4], ps = 0.f;
        #pragma unroll
        for (int j = 0; j < 4; ++j) { p[j] = __expf(sc[j] - m_new); ps += p[j]; }
        #pragma unroll
        for (int m = 1; m < 32; m <<= 1) ps += __shfl_xor(ps, m, 64);
        l_run += ps;
        m_run = m_new;
        #pragma unroll
        for (int j = 0; j < 4; ++j) {
            const int kk = j * 32 + klane;
            const float4* vr = lzV + kk * 9;
            float4 v0 = vr[0], v1 = vr[1], v2 = vr[2], v3 = vr[3], v4 = vr[4], v5 = vr[5];
            const float pj = p[j];
            acc[0] += pj*v0.x;  acc[1] += pj*v0.y;  acc[2] += pj*v0.z;  acc[3] += pj*v0.w;
            acc[4] += pj*v1.x;  acc[5] += pj*v1.y;  acc[6] += pj*v1.z;  acc[7] += pj*v1.w;
            acc[8] += pj*v2.x;  acc[9] += pj*v2.y;  acc[10] += pj*v2.z; acc[11] += pj*v2.w;
            acc[12] += pj*v3.x; acc[13] += pj*v3.y; acc[14] += pj*v3.z; acc[15] += pj*v3.w;
            acc[16] += pj*v4.x; acc[17] += pj*v4.y; acc[18] += pj*v4.z; acc[19] += pj*v4.w;
            acc[20] += pj*v5.x; acc[21] += pj*v5.y; acc[22] += pj*v5.z; acc[23] += pj*v5.w;
        }
    }
    #pragma unroll
    for (int m = 1; m < 32; m <<= 1) {
        #pragma unroll
        for (int d = 0; d < DH; ++d) acc[d] += __shfl_xor(acc[d], m, 64);
    }
    const float inv = 1.f / l_run;
    float o = 0.f;
    #pragma unroll
    for (int d = 0; d < DH; ++d) o = (klane == d) ? acc[d] : o;
    if (klane < DH) {
        float g = gt[h * N * DH + q * DH + klane];
        og[q * HD + h * DH + klane] = o * inv * g;
    }
}

// ---------------- out_gemm v3: LDS-staged og-tile, 2 cols/thread, 1536 waves (R6, kept) ----------------
__global__ void __launch_bounds__(256) out_gemm_kernel(const float* __restrict__ Wo, const float* __restrict__ bo,
                                                       const float* __restrict__ og, float* __restrict__ out) {
    __shared__ float4 lo[64 * 8];    // 8 KB
    const int t = threadIdx.x;
    const int lane = t & 63;
    const int w = __builtin_amdgcn_readfirstlane(t >> 6);
    const int s = blockIdx.x * 4 + w;     // 0..191 strips of 2 cols
    const int c0 = s * 2;
    const int m0 = blockIdx.y * 64;
    const int m = m0 + lane;
    const float4* og4 = (const float4*)og;
    float acc[2];
    acc[0] = 0.f; acc[1] = 0.f;
    for (int kb = 0; kb < HD; kb += 32) {
        __syncthreads();
        #pragma unroll
        for (int i = 0; i < 2; ++i) {
            const int idx = i * 256 + t;          // 0..511
            const int r = idx >> 3, c = idx & 7;
            lo[(r << 3) + (c ^ (r & 7))] = og4[(size_t)(m0 + r) * 96 + (kb >> 2) + c];
        }
        __syncthreads();
        float4 av[8];
        #pragma unroll
        for (int i = 0; i < 8; ++i) av[i] = lo[(lane << 3) + (i ^ (lane & 7))];
        #pragma unroll
        for (int i = 0; i < 8; ++i) {
            const float* wr = Wo + (kb + i * 4) * CS + c0; // uniform -> s_load
            #pragma unroll
            for (int j = 0; j < 2; ++j) {
                acc[j] += av[i].x * wr[j];
                acc[j] += av[i].y * wr[CS + j];
                acc[j] += av[i].z * wr[2 * CS + j];
                acc[j] += av[i].w * wr[3 * CS + j];
            }
        }
    }
    #pragma unroll
    for (int j = 0; j < 2; ++j) out[m * CS + c0 + j] = acc[j] + bo[c0 + j];
}

extern "C" void kernel_launch(void* const* d_in, const int* in_sizes, int n_in,
                              void* d_out, int out_size, void* d_ws, size_t ws_size,
                              hipStream_t stream) {
    const float* a    = (const float*)d_in[0];
    const float* z    = (const float*)d_in[1];
    const float* g_a  = (const float*)d_in[2];
    const float* b_a  = (const float*)d_in[3];
    const float* g_z  = (const float*)d_in[4];
    const float* b_z  = (const float*)d_in[5];
    const float* Wz   = (const float*)d_in[6];
    const float* bz   = (const float*)d_in[7];
    const float* Wq   = (const float*)d_in[8];
    const float* Wk   = (const float*)d_in[9];
    const float* Wv   = (const float*)d_in[10];
    const float* Wg   = (const float*)d_in[11];
    const float* bg   = (const float*)d_in[12];
    const float* Wo   = (const float*)d_in[13];
    const float* bo   = (const float*)d_in[14];
    float* ws  = (float*)d_ws;
    float* out = (float*)d_out;

    float* an   = ws + OFF_AN;
    float* qt   = ws + OFF_QT;
    float* kt   = ws + OFF_KT;
    float* vt   = ws + OFF_VT;
    float* gt   = ws + OFF_GT;
    float* ogp  = ws + OFF_OG;
    float* wz2  = ws + OFF_WZ2;
    float* shp  = ws + OFF_SH;
    float* bhp  = ws + OFF_BH;
    float* bias = ws + OFF_BIAS;

    hipLaunchKernelGGL(ln_prep_kernel, dim3(257),    dim3(256), 0, stream,
                       a, g_a, b_a, an, g_z, b_z, Wz, bz, wz2, shp, bhp);
    hipLaunchKernelGGL(qkvg_kernel,    dim3(96, 8),  dim3(256), 0, stream,
                       Wq, Wk, Wv, Wg, bg, an, qt, kt, vt, gt);
    hipLaunchKernelGGL(pairbias_kernel, dim3(4096),  dim3(256), 0, stream,
                       z, wz2, shp, bhp, bias);
    hipLaunchKernelGGL(attn_kernel,    dim3(64, 16), dim3(256), 0, stream,
                       qt, kt, vt, gt, bias, ogp);
    hipLaunchKernelGGL(out_gemm_kernel, dim3(48, 8), dim3(256), 0, stream,
                       Wo, bo, ogp, out);
}